// Round 2
// baseline (312.803 us; speedup 1.0000x reference)
//
#include <hip/hip_runtime.h>

typedef float f32x4 __attribute__((ext_vector_type(4)));
typedef _Float16 f16x8 __attribute__((ext_vector_type(8)));

#define NSEQ 2048
#define QBLK 64
#define KVBLK 64
#define KSTRIDE 200   // f16 per lds_k row (192 + 8 pad) -> 400B, 16B-aligned
#define VSTRIDE 72    // f16 per lds_vt/lds_p row (64 + 8 pad) -> 144B
#define NITER (NSEQ / KVBLK)

__device__ const int IPIDX[8] = {0, 2, 3, 4, 8, 9, 10, 14};

__global__ __launch_bounds__(256, 2)
void geoattn_kernel(const float* __restrict__ q_mv, const float* __restrict__ k_mv,
                    const float* __restrict__ v_mv, const float* __restrict__ q_s,
                    const float* __restrict__ k_s, const float* __restrict__ v_s,
                    const float* __restrict__ logw, float* __restrict__ out)
{
    __shared__ __align__(16) _Float16 lds_k[KVBLK * KSTRIDE];   // k_feat tile [64][192(+8)]
    __shared__ __align__(16) _Float16 lds_vt[288 * VSTRIDE];    // V^T tile  [288][64(+8)]
    __shared__ __align__(16) _Float16 lds_p[4 * 16 * VSTRIDE];  // per-wave P [16][64(+8)]

    const int bid  = blockIdx.x;
    // XCD-grouping: all 32 q-tiles of a head land on the same XCD (bid&7)
    const int head = (bid & 7) | ((bid >> 8) << 3);
    const int qt   = (bid >> 3) & 31;
    const int h    = head & 7;

    const int tid  = threadIdx.x;
    const int w    = tid >> 6;      // wave 0..3
    const int lane = tid & 63;
    const int lr   = lane & 15;     // A/B-frag row/col index
    const int lg   = lane >> 4;     // k-octet group

    const size_t rowbase = (size_t)head * NSEQ;
    const int q0 = qt * QBLK;

    const float scale = 0.07216878364870323f;  // 1/sqrt(192), folded into q_feat

    // ---- build Q fragments in registers (A-operand: row = lr, k = lg*8 + i + 32c) ----
    f16x8 qf[6];
    {
        const int qrow = q0 + w * 16 + lr;
        const float* qmv = q_mv + (rowbase + qrow) * 256;
        const float* qs  = q_s  + (rowbase + qrow) * 32;
        #pragma unroll
        for (int c = 0; c < 4; ++c) {
            const int cmv = 4 * c + lg;
            const float wgt = __expf(logw[h * 16 + cmv]) * scale;
            const float* p = qmv + cmv * 16;
            #pragma unroll
            for (int i = 0; i < 8; ++i)
                qf[c][i] = (_Float16)(p[IPIDX[i]] * wgt);
        }
        const int c0 = lg * 8;
        const f32x4* p4 = (const f32x4*)(qs + c0);
        f32x4 a = p4[0], b = p4[1];
        #pragma unroll
        for (int i = 0; i < 8; ++i) {
            float x = (i < 4) ? a[i & 3] : b[i & 3];
            qf[4][i] = (_Float16)(scale * x / (x * x + 1e-3f));
            qf[5][i] = (_Float16)(scale * x);
        }
    }

    f32x4 acc[18];
    #pragma unroll
    for (int dt = 0; dt < 18; ++dt) acc[dt] = f32x4{0.f, 0.f, 0.f, 0.f};
    float mrun[4] = {-1e30f, -1e30f, -1e30f, -1e30f};
    float lrun[4] = {0.f, 0.f, 0.f, 0.f};

    for (int kt = 0; kt < NITER; ++kt) {
        const int j0 = kt * KVBLK;
        __syncthreads();   // previous iter's LDS reads complete before restaging

        // ---- stage K features: 64 rows x 192 (6 octet-tasks/thread) ----
        #pragma unroll
        for (int rep = 0; rep < 6; ++rep) {
            const int t = rep * 256 + tid;
            const int j = t & 63, oct = t >> 6;   // oct is wave-uniform
            const size_t krow = rowbase + j0 + j;
            float v[8];
            if (oct < 16) {                        // IP gather, cmv = oct
                const float* p = k_mv + (krow * 16 + oct) * 16;
                #pragma unroll
                for (int i = 0; i < 8; ++i) v[i] = p[IPIDX[i]];
            } else if (oct < 20) {                 // normalizer(k_s)
                const f32x4* p4 = (const f32x4*)(k_s + krow * 32 + (oct - 16) * 8);
                f32x4 a = p4[0], b = p4[1];
                #pragma unroll
                for (int i = 0; i < 8; ++i) {
                    float x = (i < 4) ? a[i & 3] : b[i & 3];
                    v[i] = x / (x * x + 1e-3f);
                }
            } else {                               // plain k_s
                const f32x4* p4 = (const f32x4*)(k_s + krow * 32 + (oct - 20) * 8);
                f32x4 a = p4[0], b = p4[1];
                #pragma unroll
                for (int i = 0; i < 8; ++i) v[i] = (i < 4) ? a[i & 3] : b[i & 3];
            }
            f16x8 o;
            #pragma unroll
            for (int i = 0; i < 8; ++i) o[i] = (_Float16)v[i];
            *(f16x8*)(&lds_k[j * KSTRIDE + oct * 8]) = o;
        }

        // ---- stage V^T: 288 x 64 (9 octet-tasks/thread, scalar transposed writes) ----
        #pragma unroll
        for (int rep = 0; rep < 9; ++rep) {
            const int t = rep * 256 + tid;
            const int j = t & 63, oct = t >> 6;
            const size_t vrow = rowbase + j0 + j;
            const float* src = (oct < 32) ? (v_mv + vrow * 256 + oct * 8)
                                          : (v_s  + vrow * 32 + (oct - 32) * 8);
            const f32x4* p4 = (const f32x4*)src;
            f32x4 a = p4[0], b = p4[1];
            const int d0 = oct * 8;
            #pragma unroll
            for (int i = 0; i < 8; ++i)
                lds_vt[(d0 + i) * VSTRIDE + j] = (_Float16)((i < 4) ? a[i & 3] : b[i & 3]);
        }
        __syncthreads();

        // ---- S = Q K^T : 16 q-rows x 64 keys per wave ----
        f32x4 sacc[4];
        #pragma unroll
        for (int nt = 0; nt < 4; ++nt) {
            sacc[nt] = f32x4{0.f, 0.f, 0.f, 0.f};
            #pragma unroll
            for (int c = 0; c < 6; ++c) {
                f16x8 kf = *(const f16x8*)(&lds_k[(lr + 16 * nt) * KSTRIDE + 32 * c + lg * 8]);
                sacc[nt] = __builtin_amdgcn_mfma_f32_16x16x32_f16(qf[c], kf, sacc[nt], 0, 0, 0);
            }
        }

        // ---- online softmax; lane owns rows (lg*4 + r) ----
        float tmax[4], alpha[4];
        #pragma unroll
        for (int r = 0; r < 4; ++r) {
            float t0 = fmaxf(fmaxf(sacc[0][r], sacc[1][r]), fmaxf(sacc[2][r], sacc[3][r]));
            #pragma unroll
            for (int mm = 1; mm < 16; mm <<= 1)
                t0 = fmaxf(t0, __shfl_xor(t0, mm));
            tmax[r] = t0;
        }
        bool need = false;
        #pragma unroll
        for (int r = 0; r < 4; ++r) {
            float mnew = fmaxf(mrun[r], tmax[r]);
            need = need || (tmax[r] > mrun[r]);
            alpha[r] = __expf(mrun[r] - mnew);   // first iter: exp(-1e30)=0, acc is 0 anyway
            mrun[r] = mnew;
        }
        float pvv[4][4];
        float psum[4] = {0.f, 0.f, 0.f, 0.f};
        #pragma unroll
        for (int nt = 0; nt < 4; ++nt)
            #pragma unroll
            for (int r = 0; r < 4; ++r) {
                float p = __expf(sacc[nt][r] - mrun[r]);
                pvv[nt][r] = p;
                psum[r] += p;
            }
        #pragma unroll
        for (int r = 0; r < 4; ++r) {
            float s = psum[r];
            #pragma unroll
            for (int mm = 1; mm < 16; mm <<= 1) s += __shfl_xor(s, mm);
            lrun[r] = lrun[r] * alpha[r] + s;
        }
        if (__ballot(need)) {   // skip 72-mul rescale when no row max grew (wave-uniform)
            #pragma unroll
            for (int dt = 0; dt < 18; ++dt)
                #pragma unroll
                for (int r = 0; r < 4; ++r) acc[dt][r] *= alpha[r];
        }

        // ---- P -> per-wave LDS (layout fix for A-operand), then O += P V ----
        _Float16* pb = &lds_p[w * 16 * VSTRIDE];
        #pragma unroll
        for (int nt = 0; nt < 4; ++nt)
            #pragma unroll
            for (int r = 0; r < 4; ++r)
                pb[(lg * 4 + r) * VSTRIDE + lr + 16 * nt] = (_Float16)pvv[nt][r];
        // same-wave write->read; compiler inserts lgkmcnt, no barrier needed (private buffer)
        #pragma unroll
        for (int ch = 0; ch < 2; ++ch) {
            f16x8 pf = *(const f16x8*)(&pb[lr * VSTRIDE + 32 * ch + lg * 8]);
            #pragma unroll
            for (int dt = 0; dt < 18; ++dt) {
                f16x8 vf = *(const f16x8*)(&lds_vt[(lr + 16 * dt) * VSTRIDE + 32 * ch + lg * 8]);
                acc[dt] = __builtin_amdgcn_mfma_f32_16x16x32_f16(pf, vf, acc[dt], 0, 0, 0);
            }
        }
    }

    // ---- epilogue: out = acc / l ----
    const int orow = q0 + w * 16 + lg * 4;
    #pragma unroll
    for (int r = 0; r < 4; ++r) {
        const float inv = 1.0f / lrun[r];
        float* omv = out + (rowbase + orow + r) * 256;
        float* os  = out + 8388608ull + (rowbase + orow + r) * 32;
        #pragma unroll
        for (int dt = 0; dt < 18; ++dt) {
            const int d = lr + 16 * dt;
            const float val = acc[dt][r] * inv;
            if (d < 256) omv[d] = val;     // compile-time split: dt<16 -> out_mv
            else         os[d - 256] = val;
        }
    }
}

extern "C" void kernel_launch(void* const* d_in, const int* in_sizes, int n_in,
                              void* d_out, int out_size, void* d_ws, size_t ws_size,
                              hipStream_t stream) {
    (void)in_sizes; (void)n_in; (void)d_ws; (void)ws_size; (void)out_size;
    const float* q_mv = (const float*)d_in[0];
    const float* k_mv = (const float*)d_in[1];
    const float* v_mv = (const float*)d_in[2];
    const float* q_s  = (const float*)d_in[3];
    const float* k_s  = (const float*)d_in[4];
    const float* v_s  = (const float*)d_in[5];
    const float* logw = (const float*)d_in[6];
    float* out = (float*)d_out;
    geoattn_kernel<<<dim3(512), dim3(256), 0, stream>>>(q_mv, k_mv, v_mv, q_s, k_s, v_s, logw, out);
}

// Round 3
// 182.240 us; speedup vs baseline: 1.7164x; 1.7164x over previous
//
#include <hip/hip_runtime.h>

typedef float f32x4 __attribute__((ext_vector_type(4)));
typedef _Float16 f16x8 __attribute__((ext_vector_type(8)));

#define NSEQ 2048
#define QBLK 64
#define KVBLK 32
#define NITER (NSEQ / KVBLK)          // 64
#define TILEB 32768                    // ws bytes per (head, tile): kf 12288 + vt 18432 + pad
#define KFOFF 0
#define VTOFF 12288
#define PSTRIDE 40                     // f16 per lds_p row (32 + 8 pad)
#define WS_NEED (16ull * NITER * TILEB)   // 33,554,432 B

__device__ __forceinline__ void async_copy16(const void* g, void* l) {
    __builtin_amdgcn_global_load_lds((const __attribute__((address_space(1))) unsigned int*)g,
                                     (__attribute__((address_space(3))) unsigned int*)l, 16, 0, 0);
}

// ---------------- pre-pass: k features, f16, swizzled tile layout ----------------
// tile (head,kt): logical (j in [0,32), d in [0,192)) at byte (j*384 + d*2) ^ ((j&7)<<4)
__global__ __launch_bounds__(256)
void prep_kf(const float* __restrict__ k_mv, const float* __restrict__ k_s,
             unsigned char* __restrict__ ws)
{
    constexpr int IPIDX[8] = {0, 2, 3, 4, 8, 9, 10, 14};
    const int head = blockIdx.x >> 6, kt = blockIdx.x & 63;
    unsigned char* tb = ws + (size_t)(head * NITER + kt) * TILEB + KFOFF;
    const int tid = threadIdx.x;
    #pragma unroll
    for (int rep = 0; rep < 3; ++rep) {
        const int t = rep * 256 + tid;
        const int j = t & 31, oct = t >> 5;          // oct in [0,24)
        const size_t row = (size_t)head * NSEQ + kt * KVBLK + j;
        float v[8];
        if (oct < 16) {                               // IP gather, cmv = oct
            const float* p = k_mv + (row * 16 + oct) * 16;
            #pragma unroll
            for (int i = 0; i < 8; ++i) v[i] = p[IPIDX[i]];
        } else if (oct < 20) {                        // normalizer(k_s)
            const f32x4* p4 = (const f32x4*)(k_s + row * 32 + (oct - 16) * 8);
            f32x4 a = p4[0], b = p4[1];
            #pragma unroll
            for (int i = 0; i < 8; ++i) {
                float x = (i < 4) ? a[i & 3] : b[i & 3];
                v[i] = x / (x * x + 1e-3f);
            }
        } else {                                      // plain k_s
            const f32x4* p4 = (const f32x4*)(k_s + row * 32 + (oct - 20) * 8);
            f32x4 a = p4[0], b = p4[1];
            #pragma unroll
            for (int i = 0; i < 8; ++i) v[i] = (i < 4) ? a[i & 3] : b[i & 3];
        }
        f16x8 o;
        #pragma unroll
        for (int i = 0; i < 8; ++i) o[i] = (_Float16)v[i];
        *(f16x8*)(tb + ((j * 384 + oct * 16) ^ ((j & 7) << 4))) = o;
    }
}

// ---------------- pre-pass: V^T, f16, swizzled tile layout ----------------
// tile (head,kt): logical (d in [0,288), j in [0,32)) at byte (d*64 + j*2) ^ ((d&7)<<4)
__global__ __launch_bounds__(256)
void prep_vt(const float* __restrict__ v_mv, const float* __restrict__ v_s,
             unsigned char* __restrict__ ws)
{
    const int head = blockIdx.x >> 6, kt = blockIdx.x & 63;
    unsigned char* tb = ws + (size_t)(head * NITER + kt) * TILEB + VTOFF;
    const int tid = threadIdx.x;
    const size_t row0 = (size_t)head * NSEQ + kt * KVBLK;
    {
        const int d = tid;                            // 0..255 from v_mv (coalesced across lanes)
        float val[KVBLK];
        #pragma unroll
        for (int j = 0; j < KVBLK; ++j) val[j] = v_mv[(row0 + j) * 256 + d];
        #pragma unroll
        for (int jg = 0; jg < 4; ++jg) {
            f16x8 o;
            #pragma unroll
            for (int i = 0; i < 8; ++i) o[i] = (_Float16)val[jg * 8 + i];
            *(f16x8*)(tb + ((d * 64 + jg * 16) ^ ((d & 7) << 4))) = o;
        }
    }
    if (tid < 32) {                                   // d = 256..287 from v_s
        const int d = 256 + tid;
        float val[KVBLK];
        #pragma unroll
        for (int j = 0; j < KVBLK; ++j) val[j] = v_s[(row0 + j) * 32 + tid];
        #pragma unroll
        for (int jg = 0; jg < 4; ++jg) {
            f16x8 o;
            #pragma unroll
            for (int i = 0; i < 8; ++i) o[i] = (_Float16)val[jg * 8 + i];
            *(f16x8*)(tb + ((d * 64 + jg * 16) ^ ((d & 7) << 4))) = o;
        }
    }
}

// ---------------- main: flash attention over precomputed f16 tiles ----------------
__global__ __launch_bounds__(256, 2)
void geoattn_main(const float* __restrict__ q_mv, const float* __restrict__ q_s,
                  const float* __restrict__ logw, const unsigned char* __restrict__ ws,
                  float* __restrict__ out)
{
    constexpr int IPIDX[8] = {0, 2, 3, 4, 8, 9, 10, 14};
    __shared__ __align__(16) unsigned char lbuf[2][TILEB];
    __shared__ __align__(16) _Float16 lds_p[4][16 * PSTRIDE];

    const int bid  = blockIdx.x;
    const int head = (bid & 7) | ((bid >> 8) << 3);   // same-head blocks share an XCD
    const int qt   = (bid >> 3) & 31;
    const int h    = head & 7;

    const int tid  = threadIdx.x;
    const int w    = tid >> 6;
    const int lane = tid & 63;
    const int lr   = lane & 15;
    const int lg   = lane >> 4;

    const size_t rowbase = (size_t)head * NSEQ;
    const int q0 = qt * QBLK;
    const unsigned char* wsh = ws + (size_t)head * NITER * TILEB;

    const float scale = 0.07216878364870323f;  // 1/sqrt(192), folded into q_feat

    // prologue: get tile-0 DMA going before the (long) Q build
    #pragma unroll
    for (int p = 0; p < 8; ++p)
        async_copy16(wsh + p * 4096 + tid * 16, &lbuf[0][p * 4096 + tid * 16]);

    // ---- Q fragments in registers (A-operand: row = lr, k = lg*8 + i + 32c) ----
    f16x8 qf[6];
    {
        const int qrow = q0 + w * 16 + lr;
        const float* qmv = q_mv + (rowbase + qrow) * 256;
        const float* qs  = q_s  + (rowbase + qrow) * 32;
        #pragma unroll
        for (int c = 0; c < 4; ++c) {
            const int cmv = 4 * c + lg;
            const float wgt = __expf(logw[h * 16 + cmv]) * scale;
            const float* p = qmv + cmv * 16;
            #pragma unroll
            for (int i = 0; i < 8; ++i)
                qf[c][i] = (_Float16)(p[IPIDX[i]] * wgt);
        }
        const f32x4* p4 = (const f32x4*)(qs + lg * 8);
        f32x4 a = p4[0], b = p4[1];
        #pragma unroll
        for (int i = 0; i < 8; ++i) {
            float x = (i < 4) ? a[i & 3] : b[i & 3];
            qf[4][i] = (_Float16)(scale * x / (x * x + 1e-3f));
            qf[5][i] = (_Float16)(scale * x);
        }
    }

    f32x4 acc[18];
    #pragma unroll
    for (int dt = 0; dt < 18; ++dt) acc[dt] = f32x4{0.f, 0.f, 0.f, 0.f};
    float mrun[4] = {-1e30f, -1e30f, -1e30f, -1e30f};
    float lrun[4] = {0.f, 0.f, 0.f, 0.f};

    int cur = 0;
    for (int kt = 0; kt < NITER; ++kt) {
        // issue next tile's DMA into the other buffer (safe: barrier2 of prev iter)
        if (kt < NITER - 1) {
            const unsigned char* src = wsh + (size_t)(kt + 1) * TILEB;
            #pragma unroll
            for (int p = 0; p < 8; ++p)
                async_copy16(src + p * 4096 + tid * 16, &lbuf[cur ^ 1][p * 4096 + tid * 16]);
            asm volatile("s_waitcnt vmcnt(8)" ::: "memory");   // tile kt landed; kt+1 in flight
        } else {
            asm volatile("s_waitcnt vmcnt(0)" ::: "memory");
        }
        __builtin_amdgcn_s_barrier();                          // all waves' tile-kt loads done
        asm volatile("" ::: "memory");

        const unsigned char* kb = lbuf[cur];

        // ---- S = Q K^T : 16 q-rows x 32 keys per wave ----
        f32x4 sacc[2];
        #pragma unroll
        for (int jt = 0; jt < 2; ++jt) {
            sacc[jt] = f32x4{0.f, 0.f, 0.f, 0.f};
            const int j = lr + 16 * jt;
            #pragma unroll
            for (int c = 0; c < 6; ++c) {
                f16x8 kf = *(const f16x8*)(kb + KFOFF +
                            ((j * 384 + (32 * c + lg * 8) * 2) ^ ((lr & 7) << 4)));
                sacc[jt] = __builtin_amdgcn_mfma_f32_16x16x32_f16(qf[c], kf, sacc[jt], 0, 0, 0);
            }
        }

        // ---- online softmax; lane owns rows (lg*4 + r) ----
        float tmax[4], alpha[4];
        #pragma unroll
        for (int r = 0; r < 4; ++r) {
            float t0 = fmaxf(sacc[0][r], sacc[1][r]);
            #pragma unroll
            for (int mm = 1; mm < 16; mm <<= 1)
                t0 = fmaxf(t0, __shfl_xor(t0, mm));
            tmax[r] = t0;
        }
        bool need = false;
        #pragma unroll
        for (int r = 0; r < 4; ++r) {
            float mnew = fmaxf(mrun[r], tmax[r]);
            need = need || (tmax[r] > mrun[r]);
            alpha[r] = __expf(mrun[r] - mnew);
            mrun[r] = mnew;
        }
        float pvv[2][4];
        float psum[4] = {0.f, 0.f, 0.f, 0.f};
        #pragma unroll
        for (int jt = 0; jt < 2; ++jt)
            #pragma unroll
            for (int r = 0; r < 4; ++r) {
                float p = __expf(sacc[jt][r] - mrun[r]);
                pvv[jt][r] = p;
                psum[r] += p;
            }
        #pragma unroll
        for (int r = 0; r < 4; ++r) {
            float s = psum[r];
            #pragma unroll
            for (int mm = 1; mm < 16; mm <<= 1) s += __shfl_xor(s, mm);
            lrun[r] = lrun[r] * alpha[r] + s;
        }
        if (__ballot(need)) {
            #pragma unroll
            for (int dt = 0; dt < 18; ++dt)
                #pragma unroll
                for (int r = 0; r < 4; ++r) acc[dt][r] *= alpha[r];
        }

        // ---- P -> per-wave LDS (A-frag layout), then O += P V ----
        _Float16* pb = lds_p[w];
        #pragma unroll
        for (int jt = 0; jt < 2; ++jt)
            #pragma unroll
            for (int r = 0; r < 4; ++r)
                pb[(lg * 4 + r) * PSTRIDE + lr + 16 * jt] = (_Float16)pvv[jt][r];
        f16x8 pf = *(const f16x8*)(&pb[lr * PSTRIDE + lg * 8]);   // same-wave, lgkmcnt-ordered
        #pragma unroll
        for (int dt = 0; dt < 18; ++dt) {
            const int d = lr + 16 * dt;
            f16x8 vf = *(const f16x8*)(kb + VTOFF +
                        ((d * 64 + lg * 16) ^ ((lr & 7) << 4)));
            acc[dt] = __builtin_amdgcn_mfma_f32_16x16x32_f16(pf, vf, acc[dt], 0, 0, 0);
        }

        asm volatile("" ::: "memory");
        __builtin_amdgcn_s_barrier();                  // all waves done reading lbuf[cur]
        cur ^= 1;
    }

    // ---- epilogue: out = acc / l ----
    const int orow = q0 + w * 16 + lg * 4;
    #pragma unroll
    for (int r = 0; r < 4; ++r) {
        const float inv = 1.0f / lrun[r];
        float* omv = out + (rowbase + orow + r) * 256;
        float* os  = out + 8388608ull + (rowbase + orow + r) * 32;
        #pragma unroll
        for (int dt = 0; dt < 18; ++dt) {
            const int d = lr + 16 * dt;
            const float val = acc[dt][r] * inv;
            if (d < 256) omv[d] = val;
            else         os[d - 256] = val;
        }
    }
}

// ---------------- fallback (R2 kernel): used only if ws is too small ----------------
#define FKSTRIDE 200
#define FVSTRIDE 72
__global__ __launch_bounds__(256, 2)
void geoattn_fallback(const float* __restrict__ q_mv, const float* __restrict__ k_mv,
                      const float* __restrict__ v_mv, const float* __restrict__ q_s,
                      const float* __restrict__ k_s, const float* __restrict__ v_s,
                      const float* __restrict__ logw, float* __restrict__ out)
{
    constexpr int IPIDX[8] = {0, 2, 3, 4, 8, 9, 10, 14};
    __shared__ __align__(16) _Float16 lds_k[64 * FKSTRIDE];
    __shared__ __align__(16) _Float16 lds_vt[288 * FVSTRIDE];
    __shared__ __align__(16) _Float16 lds_p[4 * 16 * FVSTRIDE];

    const int bid  = blockIdx.x;
    const int head = (bid & 7) | ((bid >> 8) << 3);
    const int qt   = (bid >> 3) & 31;
    const int h    = head & 7;
    const int tid  = threadIdx.x;
    const int w    = tid >> 6;
    const int lane = tid & 63;
    const int lr   = lane & 15;
    const int lg   = lane >> 4;
    const size_t rowbase = (size_t)head * NSEQ;
    const int q0 = qt * 64;
    const float scale = 0.07216878364870323f;

    f16x8 qf[6];
    {
        const int qrow = q0 + w * 16 + lr;
        const float* qmv = q_mv + (rowbase + qrow) * 256;
        const float* qs  = q_s  + (rowbase + qrow) * 32;
        #pragma unroll
        for (int c = 0; c < 4; ++c) {
            const int cmv = 4 * c + lg;
            const float wgt = __expf(logw[h * 16 + cmv]) * scale;
            const float* p = qmv + cmv * 16;
            #pragma unroll
            for (int i = 0; i < 8; ++i) qf[c][i] = (_Float16)(p[IPIDX[i]] * wgt);
        }
        const f32x4* p4 = (const f32x4*)(qs + lg * 8);
        f32x4 a = p4[0], b = p4[1];
        #pragma unroll
        for (int i = 0; i < 8; ++i) {
            float x = (i < 4) ? a[i & 3] : b[i & 3];
            qf[4][i] = (_Float16)(scale * x / (x * x + 1e-3f));
            qf[5][i] = (_Float16)(scale * x);
        }
    }
    f32x4 acc[18];
    #pragma unroll
    for (int dt = 0; dt < 18; ++dt) acc[dt] = f32x4{0.f, 0.f, 0.f, 0.f};
    float mrun[4] = {-1e30f, -1e30f, -1e30f, -1e30f};
    float lrun[4] = {0.f, 0.f, 0.f, 0.f};

    for (int kt = 0; kt < 32; ++kt) {
        const int j0 = kt * 64;
        __syncthreads();
        #pragma unroll
        for (int rep = 0; rep < 6; ++rep) {
            const int t = rep * 256 + tid;
            const int j = t & 63, oct = t >> 6;
            const size_t krow = rowbase + j0 + j;
            float v[8];
            if (oct < 16) {
                const float* p = k_mv + (krow * 16 + oct) * 16;
                #pragma unroll
                for (int i = 0; i < 8; ++i) v[i] = p[IPIDX[i]];
            } else if (oct < 20) {
                const f32x4* p4 = (const f32x4*)(k_s + krow * 32 + (oct - 16) * 8);
                f32x4 a = p4[0], b = p4[1];
                #pragma unroll
                for (int i = 0; i < 8; ++i) {
                    float x = (i < 4) ? a[i & 3] : b[i & 3];
                    v[i] = x / (x * x + 1e-3f);
                }
            } else {
                const f32x4* p4 = (const f32x4*)(k_s + krow * 32 + (oct - 20) * 8);
                f32x4 a = p4[0], b = p4[1];
                #pragma unroll
                for (int i = 0; i < 8; ++i) v[i] = (i < 4) ? a[i & 3] : b[i & 3];
            }
            f16x8 o;
            #pragma unroll
            for (int i = 0; i < 8; ++i) o[i] = (_Float16)v[i];
            *(f16x8*)(&lds_k[j * FKSTRIDE + oct * 8]) = o;
        }
        #pragma unroll
        for (int rep = 0; rep < 9; ++rep) {
            const int t = rep * 256 + tid;
            const int j = t & 63, oct = t >> 6;
            const size_t vrow = rowbase + j0 + j;
            const float* src = (oct < 32) ? (v_mv + vrow * 256 + oct * 8)
                                          : (v_s  + vrow * 32 + (oct - 32) * 8);
            const f32x4* p4 = (const f32x4*)src;
            f32x4 a = p4[0], b = p4[1];
            const int d0 = oct * 8;
            #pragma unroll
            for (int i = 0; i < 8; ++i)
                lds_vt[(d0 + i) * FVSTRIDE + j] = (_Float16)((i < 4) ? a[i & 3] : b[i & 3]);
        }
        __syncthreads();
        f32x4 sacc[4];
        #pragma unroll
        for (int nt = 0; nt < 4; ++nt) {
            sacc[nt] = f32x4{0.f, 0.f, 0.f, 0.f};
            #pragma unroll
            for (int c = 0; c < 6; ++c) {
                f16x8 kf = *(const f16x8*)(&lds_k[(lr + 16 * nt) * FKSTRIDE + 32 * c + lg * 8]);
                sacc[nt] = __builtin_amdgcn_mfma_f32_16x16x32_f16(qf[c], kf, sacc[nt], 0, 0, 0);
            }
        }
        float tmax[4], alpha[4];
        #pragma unroll
        for (int r = 0; r < 4; ++r) {
            float t0 = fmaxf(fmaxf(sacc[0][r], sacc[1][r]), fmaxf(sacc[2][r], sacc[3][r]));
            #pragma unroll
            for (int mm = 1; mm < 16; mm <<= 1) t0 = fmaxf(t0, __shfl_xor(t0, mm));
            tmax[r] = t0;
        }
        bool need = false;
        #pragma unroll
        for (int r = 0; r < 4; ++r) {
            float mnew = fmaxf(mrun[r], tmax[r]);
            need = need || (tmax[r] > mrun[r]);
            alpha[r] = __expf(mrun[r] - mnew);
            mrun[r] = mnew;
        }
        float pvv[4][4];
        float psum[4] = {0.f, 0.f, 0.f, 0.f};
        #pragma unroll
        for (int nt = 0; nt < 4; ++nt)
            #pragma unroll
            for (int r = 0; r < 4; ++r) {
                float p = __expf(sacc[nt][r] - mrun[r]);
                pvv[nt][r] = p;
                psum[r] += p;
            }
        #pragma unroll
        for (int r = 0; r < 4; ++r) {
            float s = psum[r];
            #pragma unroll
            for (int mm = 1; mm < 16; mm <<= 1) s += __shfl_xor(s, mm);
            lrun[r] = lrun[r] * alpha[r] + s;
        }
        if (__ballot(need)) {
            #pragma unroll
            for (int dt = 0; dt < 18; ++dt)
                #pragma unroll
                for (int r = 0; r < 4; ++r) acc[dt][r] *= alpha[r];
        }
        _Float16* pb = &lds_p[w * 16 * FVSTRIDE];
        #pragma unroll
        for (int nt = 0; nt < 4; ++nt)
            #pragma unroll
            for (int r = 0; r < 4; ++r)
                pb[(lg * 4 + r) * FVSTRIDE + lr + 16 * nt] = (_Float16)pvv[nt][r];
        #pragma unroll
        for (int ch = 0; ch < 2; ++ch) {
            f16x8 pf = *(const f16x8*)(&pb[lr * FVSTRIDE + 32 * ch + lg * 8]);
            #pragma unroll
            for (int dt = 0; dt < 18; ++dt) {
                f16x8 vf = *(const f16x8*)(&lds_vt[(lr + 16 * dt) * FVSTRIDE + 32 * ch + lg * 8]);
                acc[dt] = __builtin_amdgcn_mfma_f32_16x16x32_f16(pf, vf, acc[dt], 0, 0, 0);
            }
        }
    }
    const int orow = q0 + w * 16 + lg * 4;
    #pragma unroll
    for (int r = 0; r < 4; ++r) {
        const float inv = 1.0f / lrun[r];
        float* omv = out + (rowbase + orow + r) * 256;
        float* os  = out + 8388608ull + (rowbase + orow + r) * 32;
        #pragma unroll
        for (int dt = 0; dt < 18; ++dt) {
            const int d = lr + 16 * dt;
            const float val = acc[dt][r] * inv;
            if (d < 256) omv[d] = val;
            else         os[d - 256] = val;
        }
    }
}

extern "C" void kernel_launch(void* const* d_in, const int* in_sizes, int n_in,
                              void* d_out, int out_size, void* d_ws, size_t ws_size,
                              hipStream_t stream) {
    (void)in_sizes; (void)n_in; (void)out_size;
    const float* q_mv = (const float*)d_in[0];
    const float* k_mv = (const float*)d_in[1];
    const float* v_mv = (const float*)d_in[2];
    const float* q_s  = (const float*)d_in[3];
    const float* k_s  = (const float*)d_in[4];
    const float* v_s  = (const float*)d_in[5];
    const float* logw = (const float*)d_in[6];
    float* out = (float*)d_out;

    if (ws_size >= WS_NEED) {
        unsigned char* ws = (unsigned char*)d_ws;
        prep_kf<<<dim3(1024), dim3(256), 0, stream>>>(k_mv, k_s, ws);
        prep_vt<<<dim3(1024), dim3(256), 0, stream>>>(v_mv, v_s, ws);
        geoattn_main<<<dim3(512), dim3(256), 0, stream>>>(q_mv, q_s, logw, ws, out);
    } else {
        geoattn_fallback<<<dim3(512), dim3(256), 0, stream>>>(q_mv, k_mv, v_mv, q_s, k_s, v_s, logw, out);
    }
}

// Round 4
// 163.840 us; speedup vs baseline: 1.9092x; 1.1123x over previous
//
#include <hip/hip_runtime.h>

typedef float f32x4 __attribute__((ext_vector_type(4)));
typedef _Float16 f16x8 __attribute__((ext_vector_type(8)));
typedef _Float16 f16x4 __attribute__((ext_vector_type(4)));

#define NSEQ 2048
#define KVBLK 64
#define NITER (NSEQ / KVBLK)        // 32
#define KFBYTES (KVBLK * 384)       // 24576  (64 keys x 192 dims f16)
#define VTBYTES (288 * 2 * KVBLK)   // 36864  (288 dims x 64 keys f16)
#define TILEB (KFBYTES + VTBYTES)   // 61440 = 15 * 4096
#define KFOFF 0
#define VTOFF KFBYTES
#define NCHUNK (TILEB / 4096)       // 15 global_load_lds x16B per thread per tile
#define PSTRIDE 72                  // f16 per P row (64 + 8 pad) -> 144B
#define WS_NEED (16ull * NITER * TILEB)   // 31,457,280 B

#define SCALE_L2E 0.10411754f       // log2(e)/sqrt(192): softmax done in exp2 domain
#define DEFER_THR 11.0f             // defer-max threshold (log2 units); P <= 2^11 ok in f16

__device__ __forceinline__ void async_copy16(const void* g, void* l) {
    __builtin_amdgcn_global_load_lds((const __attribute__((address_space(1))) unsigned int*)g,
                                     (__attribute__((address_space(3))) unsigned int*)l, 16, 0, 0);
}

// ---------------- pre-pass: k features, f16, swizzled tile ----------------
// tile (head,kt): logical (j in [0,64), d in [0,192)) at byte (j*384 + d*2) ^ ((j&7)<<4)
__global__ __launch_bounds__(256)
void prep_kf(const float* __restrict__ k_mv, const float* __restrict__ k_s,
             unsigned char* __restrict__ ws)
{
    constexpr int IPIDX[8] = {0, 2, 3, 4, 8, 9, 10, 14};
    const int head = blockIdx.x >> 5, kt = blockIdx.x & 31;
    unsigned char* tb = ws + (size_t)(head * NITER + kt) * TILEB + KFOFF;
    const int tid = threadIdx.x;
    #pragma unroll
    for (int rep = 0; rep < 6; ++rep) {
        const int t = rep * 256 + tid;
        const int j = t & 63, oct = t >> 6;           // oct in [0,24)
        const size_t row = (size_t)head * NSEQ + kt * KVBLK + j;
        float v[8];
        if (oct < 16) {                                // IP gather, cmv = oct
            const float* p = k_mv + (row * 16 + oct) * 16;
            #pragma unroll
            for (int i = 0; i < 8; ++i) v[i] = p[IPIDX[i]];
        } else if (oct < 20) {                         // normalizer(k_s)
            const f32x4* p4 = (const f32x4*)(k_s + row * 32 + (oct - 16) * 8);
            f32x4 a = p4[0], b = p4[1];
            #pragma unroll
            for (int i = 0; i < 8; ++i) {
                float x = (i < 4) ? a[i & 3] : b[i & 3];
                v[i] = x / (x * x + 1e-3f);
            }
        } else {                                       // plain k_s
            const f32x4* p4 = (const f32x4*)(k_s + row * 32 + (oct - 20) * 8);
            f32x4 a = p4[0], b = p4[1];
            #pragma unroll
            for (int i = 0; i < 8; ++i) v[i] = (i < 4) ? a[i & 3] : b[i & 3];
        }
        f16x8 o;
        #pragma unroll
        for (int i = 0; i < 8; ++i) o[i] = (_Float16)v[i];
        *(f16x8*)(tb + ((j * 384 + oct * 16) ^ ((j & 7) << 4))) = o;
    }
}

// ---------------- pre-pass: V^T, f16, swizzled tile ----------------
// tile (head,kt): logical (d in [0,288), j in [0,64)) at byte (d*128 + j*2) ^ ((d&7)<<4)
__global__ __launch_bounds__(256)
void prep_vt(const float* __restrict__ v_mv, const float* __restrict__ v_s,
             unsigned char* __restrict__ ws)
{
    const int head = blockIdx.x >> 5, kt = blockIdx.x & 31;
    unsigned char* tb = ws + (size_t)(head * NITER + kt) * TILEB + VTOFF;
    const int tid = threadIdx.x;
    const size_t row0 = (size_t)head * NSEQ + kt * KVBLK;
    {
        const int d = tid;                             // 0..255 from v_mv
        float val[KVBLK];
        #pragma unroll
        for (int j = 0; j < KVBLK; ++j) val[j] = v_mv[(row0 + j) * 256 + d];
        #pragma unroll
        for (int jg = 0; jg < 8; ++jg) {
            f16x8 o;
            #pragma unroll
            for (int i = 0; i < 8; ++i) o[i] = (_Float16)val[jg * 8 + i];
            *(f16x8*)(tb + ((d * 128 + jg * 16) ^ ((d & 7) << 4))) = o;
        }
    }
    if (tid < 32) {                                    // d = 256..287 from v_s
        const int d = 256 + tid;
        float val[KVBLK];
        #pragma unroll
        for (int j = 0; j < KVBLK; ++j) val[j] = v_s[(row0 + j) * 32 + tid];
        #pragma unroll
        for (int jg = 0; jg < 8; ++jg) {
            f16x8 o;
            #pragma unroll
            for (int i = 0; i < 8; ++i) o[i] = (_Float16)val[jg * 8 + i];
            *(f16x8*)(tb + ((d * 128 + jg * 16) ^ ((d & 7) << 4))) = o;
        }
    }
}

// ---------------- main: 256 blocks, 4 waves, 32 q-rows/wave, swapped QK^T ----------------
__global__ __launch_bounds__(256, 1)
void geoattn_main(const float* __restrict__ q_mv, const float* __restrict__ q_s,
                  const float* __restrict__ logw, const unsigned char* __restrict__ ws,
                  float* __restrict__ out)
{
    constexpr int IPIDX[8] = {0, 2, 3, 4, 8, 9, 10, 14};
    __shared__ __align__(16) unsigned char lbuf[2][TILEB];
    __shared__ __align__(16) _Float16 pball[4][32 * PSTRIDE];

    const int bid  = blockIdx.x;                       // 256 blocks
    const int head = (bid & 7) | ((bid >> 7) << 3);    // same-head blocks share an XCD
    const int qt   = (bid >> 3) & 15;
    const int h    = head & 7;

    const int tid  = threadIdx.x;
    const int w    = tid >> 6;
    const int lane = tid & 63;
    const int lr   = lane & 15;
    const int lg   = lane >> 4;

    const size_t rowbase = (size_t)head * NSEQ;
    const int q0 = qt * 128;
    const unsigned char* wsh = ws + (size_t)head * NITER * TILEB;

    // prologue: tile-0 DMA before the Q build
    #pragma unroll
    for (int p = 0; p < NCHUNK; ++p)
        async_copy16(wsh + p * 4096 + tid * 16, &lbuf[0][p * 4096 + tid * 16]);

    // ---- Q fragments (B-operand: col = lr = q-row, k = lg*8 + i + 32c), 2 row-groups ----
    f16x8 qf[2][6];
    #pragma unroll
    for (int rg = 0; rg < 2; ++rg) {
        const int qrow = q0 + w * 32 + rg * 16 + lr;
        const float* qmv = q_mv + (rowbase + qrow) * 256;
        const float* qs  = q_s  + (rowbase + qrow) * 32;
        #pragma unroll
        for (int c = 0; c < 4; ++c) {
            const int cmv = 4 * c + lg;
            const float wgt = __expf(logw[h * 16 + cmv]) * SCALE_L2E;
            const float* p = qmv + cmv * 16;
            #pragma unroll
            for (int i = 0; i < 8; ++i)
                qf[rg][c][i] = (_Float16)(p[IPIDX[i]] * wgt);
        }
        const f32x4* p4 = (const f32x4*)(qs + lg * 8);
        f32x4 a = p4[0], b = p4[1];
        #pragma unroll
        for (int i = 0; i < 8; ++i) {
            float x = (i < 4) ? a[i & 3] : b[i & 3];
            qf[rg][4][i] = (_Float16)(SCALE_L2E * x / (x * x + 1e-3f));
            qf[rg][5][i] = (_Float16)(SCALE_L2E * x);
        }
    }

    f32x4 acc[2][18];
    #pragma unroll
    for (int rg = 0; rg < 2; ++rg)
        #pragma unroll
        for (int dt = 0; dt < 18; ++dt) acc[rg][dt] = f32x4{0.f, 0.f, 0.f, 0.f};
    float mrun[2] = {-1e30f, -1e30f};
    float lrun[2] = {0.f, 0.f};

    _Float16* pb = &pball[w][0];

    int cur = 0;
    for (int kt = 0; kt < NITER; ++kt) {
        if (kt < NITER - 1) {
            const unsigned char* src = wsh + (size_t)(kt + 1) * TILEB;
            #pragma unroll
            for (int p = 0; p < NCHUNK; ++p)
                async_copy16(src + p * 4096 + tid * 16, &lbuf[cur ^ 1][p * 4096 + tid * 16]);
            asm volatile("s_waitcnt vmcnt(15)" ::: "memory");   // tile kt landed; kt+1 in flight
        } else {
            asm volatile("s_waitcnt vmcnt(0)" ::: "memory");
        }
        __builtin_amdgcn_s_barrier();
        asm volatile("" ::: "memory");

        const unsigned char* kb = lbuf[cur];

        // ---- S^T = K Q : A = k_feat (keys), B = Q. Lane holds P-row of q-row lr ----
        f32x4 sacc[2][4];
        #pragma unroll
        for (int rg = 0; rg < 2; ++rg)
            #pragma unroll
            for (int jt = 0; jt < 4; ++jt) sacc[rg][jt] = f32x4{0.f, 0.f, 0.f, 0.f};
        #pragma unroll
        for (int jt = 0; jt < 4; ++jt) {
            const int j = jt * 16 + lr;                 // key row
            #pragma unroll
            for (int c = 0; c < 6; ++c) {
                f16x8 kf = *(const f16x8*)(kb + KFOFF +
                            ((j * 384 + c * 64 + lg * 16) ^ ((lr & 7) << 4)));
                sacc[0][jt] = __builtin_amdgcn_mfma_f32_16x16x32_f16(kf, qf[0][c], sacc[0][jt], 0, 0, 0);
                sacc[1][jt] = __builtin_amdgcn_mfma_f32_16x16x32_f16(kf, qf[1][c], sacc[1][jt], 0, 0, 0);
            }
        }

        // ---- softmax (exp2 domain). Lane owns q-row lr of each row-group ----
        float mloc[2];
        #pragma unroll
        for (int rg = 0; rg < 2; ++rg) {
            float t0 = fmaxf(fmaxf(sacc[rg][0][0], sacc[rg][0][1]), fmaxf(sacc[rg][0][2], sacc[rg][0][3]));
            #pragma unroll
            for (int jt = 1; jt < 4; ++jt) {
                float t1 = fmaxf(fmaxf(sacc[rg][jt][0], sacc[rg][jt][1]), fmaxf(sacc[rg][jt][2], sacc[rg][jt][3]));
                t0 = fmaxf(t0, t1);
            }
            t0 = fmaxf(t0, __shfl_xor(t0, 16));
            t0 = fmaxf(t0, __shfl_xor(t0, 32));
            mloc[rg] = t0;
        }
        const bool need = (mloc[0] > mrun[0] + DEFER_THR) || (mloc[1] > mrun[1] + DEFER_THR);
        if (__ballot(need)) {                           // rare after first iters (defer-max)
            #pragma unroll
            for (int rg = 0; rg < 2; ++rg) {
                const float mnew = fmaxf(mrun[rg], mloc[rg]);
                const float al = exp2f(mrun[rg] - mnew);
                mrun[rg] = mnew;
                lrun[rg] *= al;
                float ar[4];
                #pragma unroll
                for (int r = 0; r < 4; ++r) ar[r] = __shfl(al, lg * 4 + r, 16);
                #pragma unroll
                for (int dt = 0; dt < 18; ++dt)
                    #pragma unroll
                    for (int r = 0; r < 4; ++r) acc[rg][dt][r] *= ar[r];
            }
        }
        #pragma unroll
        for (int rg = 0; rg < 2; ++rg) {
            float ps = 0.f;
            f16x4 pk[4];
            #pragma unroll
            for (int jt = 0; jt < 4; ++jt)
                #pragma unroll
                for (int r = 0; r < 4; ++r) {
                    const float p = exp2f(sacc[rg][jt][r] - mrun[rg]);
                    ps += p;
                    pk[jt][r] = (_Float16)p;
                }
            ps += __shfl_xor(ps, 16);
            ps += __shfl_xor(ps, 32);
            lrun[rg] += ps;
            #pragma unroll
            for (int jt = 0; jt < 4; ++jt)
                *(f16x4*)(&pb[(rg * 16 + lr) * PSTRIDE + jt * 16 + lg * 4]) = pk[jt];
        }

        // ---- O += P V  (A = P from per-wave LDS, B = V^T tile; vf shared across rg) ----
        #pragma unroll
        for (int kc = 0; kc < 2; ++kc) {
            f16x8 pf0 = *(const f16x8*)(&pb[lr * PSTRIDE + kc * 32 + lg * 8]);
            f16x8 pf1 = *(const f16x8*)(&pb[(16 + lr) * PSTRIDE + kc * 32 + lg * 8]);
            #pragma unroll
            for (int dt = 0; dt < 18; ++dt) {
                const int d = dt * 16 + lr;
                f16x8 vf = *(const f16x8*)(kb + VTOFF +
                            ((d * 128 + kc * 64 + lg * 16) ^ ((lr & 7) << 4)));
                acc[0][dt] = __builtin_amdgcn_mfma_f32_16x16x32_f16(pf0, vf, acc[0][dt], 0, 0, 0);
                acc[1][dt] = __builtin_amdgcn_mfma_f32_16x16x32_f16(pf1, vf, acc[1][dt], 0, 0, 0);
            }
        }

        asm volatile("" ::: "memory");
        __builtin_amdgcn_s_barrier();                   // all waves done with lbuf[cur]
        cur ^= 1;
    }

    // ---- epilogue: out = acc / l  (l redistributed from q-row owner lanes) ----
    #pragma unroll
    for (int rg = 0; rg < 2; ++rg) {
        const float inv = 1.0f / lrun[rg];
        float invr[4];
        #pragma unroll
        for (int r = 0; r < 4; ++r) invr[r] = __shfl(inv, lg * 4 + r, 16);
        #pragma unroll
        for (int r = 0; r < 4; ++r) {
            const int orow = q0 + w * 32 + rg * 16 + lg * 4 + r;
            float* omv = out + (rowbase + orow) * 256;
            float* os  = out + 8388608ull + (rowbase + orow) * 32;
            #pragma unroll
            for (int dt = 0; dt < 18; ++dt) {
                const int d = dt * 16 + lr;
                const float val = acc[rg][dt][r] * invr[r];
                if (d < 256) omv[d] = val;
                else         os[d - 256] = val;
            }
        }
    }
}

// ---------------- fallback (R2 kernel): used only if ws is too small ----------------
#define FKSTRIDE 200
#define FVSTRIDE 72
__global__ __launch_bounds__(256, 2)
void geoattn_fallback(const float* __restrict__ q_mv, const float* __restrict__ k_mv,
                      const float* __restrict__ v_mv, const float* __restrict__ q_s,
                      const float* __restrict__ k_s, const float* __restrict__ v_s,
                      const float* __restrict__ logw, float* __restrict__ out)
{
    constexpr int IPIDX[8] = {0, 2, 3, 4, 8, 9, 10, 14};
    __shared__ __align__(16) _Float16 lds_k[64 * FKSTRIDE];
    __shared__ __align__(16) _Float16 lds_vt[288 * FVSTRIDE];
    __shared__ __align__(16) _Float16 lds_p[4 * 16 * FVSTRIDE];

    const int bid  = blockIdx.x;
    const int head = (bid & 7) | ((bid >> 8) << 3);
    const int qt   = (bid >> 3) & 31;
    const int h    = head & 7;
    const int tid  = threadIdx.x;
    const int w    = tid >> 6;
    const int lane = tid & 63;
    const int lr   = lane & 15;
    const int lg   = lane >> 4;
    const size_t rowbase = (size_t)head * NSEQ;
    const int q0 = qt * 64;
    const float scale = 0.07216878364870323f;

    f16x8 qf[6];
    {
        const int qrow = q0 + w * 16 + lr;
        const float* qmv = q_mv + (rowbase + qrow) * 256;
        const float* qs  = q_s  + (rowbase + qrow) * 32;
        #pragma unroll
        for (int c = 0; c < 4; ++c) {
            const int cmv = 4 * c + lg;
            const float wgt = __expf(logw[h * 16 + cmv]) * scale;
            const float* p = qmv + cmv * 16;
            #pragma unroll
            for (int i = 0; i < 8; ++i) qf[c][i] = (_Float16)(p[IPIDX[i]] * wgt);
        }
        const f32x4* p4 = (const f32x4*)(qs + lg * 8);
        f32x4 a = p4[0], b = p4[1];
        #pragma unroll
        for (int i = 0; i < 8; ++i) {
            float x = (i < 4) ? a[i & 3] : b[i & 3];
            qf[4][i] = (_Float16)(scale * x / (x * x + 1e-3f));
            qf[5][i] = (_Float16)(scale * x);
        }
    }
    f32x4 acc[18];
    #pragma unroll
    for (int dt = 0; dt < 18; ++dt) acc[dt] = f32x4{0.f, 0.f, 0.f, 0.f};
    float mrun[4] = {-1e30f, -1e30f, -1e30f, -1e30f};
    float lrun[4] = {0.f, 0.f, 0.f, 0.f};

    for (int kt = 0; kt < 32; ++kt) {
        const int j0 = kt * 64;
        __syncthreads();
        #pragma unroll
        for (int rep = 0; rep < 6; ++rep) {
            const int t = rep * 256 + tid;
            const int j = t & 63, oct = t >> 6;
            const size_t krow = rowbase + j0 + j;
            float v[8];
            if (oct < 16) {
                const float* p = k_mv + (krow * 16 + oct) * 16;
                #pragma unroll
                for (int i = 0; i < 8; ++i) v[i] = p[IPIDX[i]];
            } else if (oct < 20) {
                const f32x4* p4 = (const f32x4*)(k_s + krow * 32 + (oct - 16) * 8);
                f32x4 a = p4[0], b = p4[1];
                #pragma unroll
                for (int i = 0; i < 8; ++i) {
                    float x = (i < 4) ? a[i & 3] : b[i & 3];
                    v[i] = x / (x * x + 1e-3f);
                }
            } else {
                const f32x4* p4 = (const f32x4*)(k_s + krow * 32 + (oct - 20) * 8);
                f32x4 a = p4[0], b = p4[1];
                #pragma unroll
                for (int i = 0; i < 8; ++i) v[i] = (i < 4) ? a[i & 3] : b[i & 3];
            }
            f16x8 o;
            #pragma unroll
            for (int i = 0; i < 8; ++i) o[i] = (_Float16)v[i];
            *(f16x8*)(&lds_k[j * FKSTRIDE + oct * 8]) = o;
        }
        #pragma unroll
        for (int rep = 0; rep < 9; ++rep) {
            const int t = rep * 256 + tid;
            const int j = t & 63, oct = t >> 6;
            const size_t vrow = rowbase + j0 + j;
            const float* src = (oct < 32) ? (v_mv + vrow * 256 + oct * 8)
                                          : (v_s  + vrow * 32 + (oct - 32) * 8);
            const f32x4* p4 = (const f32x4*)src;
            f32x4 a = p4[0], b = p4[1];
            const int d0 = oct * 8;
            #pragma unroll
            for (int i = 0; i < 8; ++i)
                lds_vt[(d0 + i) * FVSTRIDE + j] = (_Float16)((i < 4) ? a[i & 3] : b[i & 3]);
        }
        __syncthreads();
        f32x4 sacc[4];
        #pragma unroll
        for (int nt = 0; nt < 4; ++nt) {
            sacc[nt] = f32x4{0.f, 0.f, 0.f, 0.f};
            #pragma unroll
            for (int c = 0; c < 6; ++c) {
                f16x8 kf = *(const f16x8*)(&lds_k[(lr + 16 * nt) * FKSTRIDE + 32 * c + lg * 8]);
                sacc[nt] = __builtin_amdgcn_mfma_f32_16x16x32_f16(qf[c], kf, sacc[nt], 0, 0, 0);
            }
        }
        float tmax[4], alpha[4];
        #pragma unroll
        for (int r = 0; r < 4; ++r) {
            float t0 = fmaxf(fmaxf(sacc[0][r], sacc[1][r]), fmaxf(sacc[2][r], sacc[3][r]));
            #pragma unroll
            for (int mm = 1; mm < 16; mm <<= 1) t0 = fmaxf(t0, __shfl_xor(t0, mm));
            tmax[r] = t0;
        }
        bool need = false;
        #pragma unroll
        for (int r = 0; r < 4; ++r) {
            float mnew = fmaxf(mrun[r], tmax[r]);
            need = need || (tmax[r] > mrun[r]);
            alpha[r] = __expf(mrun[r] - mnew);
            mrun[r] = mnew;
        }
        float pvv[4][4];
        float psum[4] = {0.f, 0.f, 0.f, 0.f};
        #pragma unroll
        for (int nt = 0; nt < 4; ++nt)
            #pragma unroll
            for (int r = 0; r < 4; ++r) {
                float p = __expf(sacc[nt][r] - mrun[r]);
                pvv[nt][r] = p;
                psum[r] += p;
            }
        #pragma unroll
        for (int r = 0; r < 4; ++r) {
            float s = psum[r];
            #pragma unroll
            for (int mm = 1; mm < 16; mm <<= 1) s += __shfl_xor(s, mm);
            lrun[r] = lrun[r] * alpha[r] + s;
        }
        if (__ballot(need)) {
            #pragma unroll
            for (int dt = 0; dt < 18; ++dt)
                #pragma unroll
                for (int r = 0; r < 4; ++r) acc[dt][r] *= alpha[r];
        }
        _Float16* pbf = &lds_p[w * 16 * FVSTRIDE];
        #pragma unroll
        for (int nt = 0; nt < 4; ++nt)
            #pragma unroll
            for (int r = 0; r < 4; ++r)
                pbf[(lg * 4 + r) * FVSTRIDE + lr + 16 * nt] = (_Float16)pvv[nt][r];
        #pragma unroll
        for (int ch = 0; ch < 2; ++ch) {
            f16x8 pf = *(const f16x8*)(&pbf[lr * FVSTRIDE + 32 * ch + lg * 8]);
            #pragma unroll
            for (int dt = 0; dt < 18; ++dt) {
                f16x8 vf = *(const f16x8*)(&lds_vt[(lr + 16 * dt) * FVSTRIDE + 32 * ch + lg * 8]);
                acc[dt] = __builtin_amdgcn_mfma_f32_16x16x32_f16(pf, vf, acc[dt], 0, 0, 0);
            }
        }
    }
    const int orow = q0 + w * 16 + lg * 4;
    #pragma unroll
    for (int r = 0; r < 4; ++r) {
        const float inv = 1.0f / lrun[r];
        float* omv = out + (rowbase + orow + r) * 256;
        float* os  = out + 8388608ull + (rowbase + orow + r) * 32;
        #pragma unroll
        for (int dt = 0; dt < 18; ++dt) {
            const int d = lr + 16 * dt;
            const float val = acc[dt][r] * inv;
            if (d < 256) omv[d] = val;
            else         os[d - 256] = val;
        }
    }
}

extern "C" void kernel_launch(void* const* d_in, const int* in_sizes, int n_in,
                              void* d_out, int out_size, void* d_ws, size_t ws_size,
                              hipStream_t stream) {
    (void)in_sizes; (void)n_in; (void)out_size;
    const float* q_mv = (const float*)d_in[0];
    const float* k_mv = (const float*)d_in[1];
    const float* v_mv = (const float*)d_in[2];
    const float* q_s  = (const float*)d_in[3];
    const float* k_s  = (const float*)d_in[4];
    const float* v_s  = (const float*)d_in[5];
    const float* logw = (const float*)d_in[6];
    float* out = (float*)d_out;

    if (ws_size >= WS_NEED) {
        unsigned char* ws = (unsigned char*)d_ws;
        prep_kf<<<dim3(512), dim3(256), 0, stream>>>(k_mv, k_s, ws);
        prep_vt<<<dim3(512), dim3(256), 0, stream>>>(v_mv, v_s, ws);
        geoattn_main<<<dim3(256), dim3(256), 0, stream>>>(q_mv, q_s, logw, ws, out);
    } else {
        geoattn_fallback<<<dim3(512), dim3(256), 0, stream>>>(q_mv, k_mv, v_mv, q_s, k_s, v_s, logw, out);
    }
}

// Round 5
// 125.328 us; speedup vs baseline: 2.4959x; 1.3073x over previous
//
#include <hip/hip_runtime.h>

typedef float f32x4 __attribute__((ext_vector_type(4)));
typedef _Float16 f16x8 __attribute__((ext_vector_type(8)));
typedef _Float16 f16x4 __attribute__((ext_vector_type(4)));

#define NSEQ 2048
#define KVBLK 64
#define NITER (NSEQ / KVBLK)        // 32
#define KFBYTES (KVBLK * 384)       // 24576  (64 keys x 192 dims f16)
#define VTBYTES (288 * 2 * KVBLK)   // 36864  (288 dims x 64 keys f16)
#define TILEB (KFBYTES + VTBYTES)   // 61440
#define KFOFF 0
#define VTOFF KFBYTES
#define PSTRIDE 72                  // f16 per P row (64 + 8 pad) -> 144B
#define WS_NEED (16ull * NITER * TILEB)   // 31,457,280 B

#define SCALE_L2E 0.10411754f       // log2(e)/sqrt(192): softmax in exp2 domain
#define DEFER_THR 11.0f             // defer-max threshold (log2 units); P <= 2^11 ok in f16

__device__ __forceinline__ void async_copy16(const void* g, void* l) {
    __builtin_amdgcn_global_load_lds((const __attribute__((address_space(1))) unsigned int*)g,
                                     (__attribute__((address_space(3))) unsigned int*)l, 16, 0, 0);
}

// ---------------- pre-pass: k features, f16, swizzled tile ----------------
// tile (head,kt): logical (j in [0,64), d in [0,192)) at byte (j*384 + d*2) ^ ((j&7)<<4)
__global__ __launch_bounds__(256)
void prep_kf(const float* __restrict__ k_mv, const float* __restrict__ k_s,
             unsigned char* __restrict__ ws)
{
    constexpr int IPIDX[8] = {0, 2, 3, 4, 8, 9, 10, 14};
    const int head = blockIdx.x >> 5, kt = blockIdx.x & 31;
    unsigned char* tb = ws + (size_t)(head * NITER + kt) * TILEB + KFOFF;
    const int tid = threadIdx.x;
    #pragma unroll
    for (int rep = 0; rep < 6; ++rep) {
        const int t = rep * 256 + tid;
        const int j = t & 63, oct = t >> 6;           // oct in [0,24)
        const size_t row = (size_t)head * NSEQ + kt * KVBLK + j;
        float v[8];
        if (oct < 16) {                                // IP gather, cmv = oct
            const float* p = k_mv + (row * 16 + oct) * 16;
            #pragma unroll
            for (int i = 0; i < 8; ++i) v[i] = p[IPIDX[i]];
        } else if (oct < 20) {                         // normalizer(k_s)
            const f32x4* p4 = (const f32x4*)(k_s + row * 32 + (oct - 16) * 8);
            f32x4 a = p4[0], b = p4[1];
            #pragma unroll
            for (int i = 0; i < 8; ++i) {
                float x = (i < 4) ? a[i & 3] : b[i & 3];
                v[i] = x / (x * x + 1e-3f);
            }
        } else {                                       // plain k_s
            const f32x4* p4 = (const f32x4*)(k_s + row * 32 + (oct - 20) * 8);
            f32x4 a = p4[0], b = p4[1];
            #pragma unroll
            for (int i = 0; i < 8; ++i) v[i] = (i < 4) ? a[i & 3] : b[i & 3];
        }
        f16x8 o;
        #pragma unroll
        for (int i = 0; i < 8; ++i) o[i] = (_Float16)v[i];
        *(f16x8*)(tb + ((j * 384 + oct * 16) ^ ((j & 7) << 4))) = o;
    }
}

// ---------------- pre-pass: V^T, f16, swizzled tile ----------------
// tile (head,kt): logical (d in [0,288), j in [0,64)) at byte (d*128 + j*2) ^ ((d&7)<<4)
__global__ __launch_bounds__(256)
void prep_vt(const float* __restrict__ v_mv, const float* __restrict__ v_s,
             unsigned char* __restrict__ ws)
{
    const int head = blockIdx.x >> 5, kt = blockIdx.x & 31;
    unsigned char* tb = ws + (size_t)(head * NITER + kt) * TILEB + VTOFF;
    const int tid = threadIdx.x;
    const size_t row0 = (size_t)head * NSEQ + kt * KVBLK;
    {
        const int d = tid;                             // 0..255 from v_mv
        float val[KVBLK];
        #pragma unroll
        for (int j = 0; j < KVBLK; ++j) val[j] = v_mv[(row0 + j) * 256 + d];
        #pragma unroll
        for (int jg = 0; jg < 8; ++jg) {
            f16x8 o;
            #pragma unroll
            for (int i = 0; i < 8; ++i) o[i] = (_Float16)val[jg * 8 + i];
            *(f16x8*)(tb + ((d * 128 + jg * 16) ^ ((d & 7) << 4))) = o;
        }
    }
    if (tid < 32) {                                    // d = 256..287 from v_s
        const int d = 256 + tid;
        float val[KVBLK];
        #pragma unroll
        for (int j = 0; j < KVBLK; ++j) val[j] = v_s[(row0 + j) * 32 + tid];
        #pragma unroll
        for (int jg = 0; jg < 8; ++jg) {
            f16x8 o;
            #pragma unroll
            for (int i = 0; i < 8; ++i) o[i] = (_Float16)val[jg * 8 + i];
            *(f16x8*)(tb + ((d * 128 + jg * 16) ^ ((d & 7) << 4))) = o;
        }
    }
}

// ---- main: 256 blocks x 512 threads (8 waves, 2/SIMD). Wave: S+softmax for 16
// q-rows; PV pair-split (32 rows x 144 dims). ----
__global__ __launch_bounds__(512, 2)
void geoattn_main(const float* __restrict__ q_mv, const float* __restrict__ q_s,
                  const float* __restrict__ logw, const unsigned char* __restrict__ ws,
                  float* __restrict__ out)
{
    constexpr int IPIDX[8] = {0, 2, 3, 4, 8, 9, 10, 14};
    __shared__ __align__(16) unsigned char lbuf[2][TILEB];
    __shared__ __align__(16) _Float16 P_lds[128 * PSTRIDE];
    __shared__ __align__(16) float a_lds[128];         // per-row alpha (iters) / l (epilogue)

    const int bid  = blockIdx.x;                       // 256 blocks
    const int head = (bid & 7) | ((bid >> 7) << 3);    // same-head blocks share an XCD
    const int qt   = (bid >> 3) & 15;
    const int h    = head & 7;

    const int tid  = threadIdx.x;
    const int w    = tid >> 6;       // 0..7
    const int lane = tid & 63;
    const int lr   = lane & 15;
    const int lg   = lane >> 4;
    const int pr   = (w >> 1) * 32;  // pair row base within block
    const int e    = w & 1;          // dim-half for PV

    const size_t rowbase = (size_t)head * NSEQ;
    const int q0 = qt * 128;
    const unsigned char* wsh = ws + (size_t)head * NITER * TILEB;

    // prologue: tile-0 DMA before the Q build (waves 0-3: 8 chunks, waves 4-7: 7)
    #pragma unroll
    for (int c = 0; c < 8; ++c) {
        const int off = c * 8192 + tid * 16;
        if (off < TILEB) async_copy16(wsh + off, &lbuf[0][off]);
    }

    // ---- Q fragment (B-operand: col = lr = q-row, k = lg*8 + i + 32c) ----
    f16x8 qf[6];
    {
        const int qrow = q0 + w * 16 + lr;
        const float* qmv = q_mv + (rowbase + qrow) * 256;
        const float* qs  = q_s  + (rowbase + qrow) * 32;
        #pragma unroll
        for (int c = 0; c < 4; ++c) {
            const int cmv = 4 * c + lg;
            const float wgt = __expf(logw[h * 16 + cmv]) * SCALE_L2E;
            const float* p = qmv + cmv * 16;
            #pragma unroll
            for (int i = 0; i < 8; ++i)
                qf[c][i] = (_Float16)(p[IPIDX[i]] * wgt);
        }
        const f32x4* p4 = (const f32x4*)(qs + lg * 8);
        f32x4 a = p4[0], b = p4[1];
        #pragma unroll
        for (int i = 0; i < 8; ++i) {
            float x = (i < 4) ? a[i & 3] : b[i & 3];
            qf[4][i] = (_Float16)(SCALE_L2E * x / (x * x + 1e-3f));
            qf[5][i] = (_Float16)(SCALE_L2E * x);
        }
    }

    f32x4 acc[2][9];                  // pair rows (2 rg) x 144 dims (9 dt)
    #pragma unroll
    for (int rg = 0; rg < 2; ++rg)
        #pragma unroll
        for (int dt = 0; dt < 9; ++dt) acc[rg][dt] = f32x4{0.f, 0.f, 0.f, 0.f};
    float mrun = -1e30f, lrun = 0.f;  // for own 16 q-rows (lane owns row lr)

    int cur = 0;
    for (int kt = 0; kt < NITER; ++kt) {
        if (kt < NITER - 1) {
            const unsigned char* src = wsh + (size_t)(kt + 1) * TILEB;
            #pragma unroll
            for (int c = 0; c < 8; ++c) {
                const int off = c * 8192 + tid * 16;
                if (off < TILEB) async_copy16(src + off, &lbuf[cur ^ 1][off]);
            }
            asm volatile("s_waitcnt vmcnt(7)" ::: "memory");   // tile kt landed; kt+1 in flight
        } else {
            asm volatile("s_waitcnt vmcnt(0)" ::: "memory");
        }
        __builtin_amdgcn_s_barrier();                          // B1: tile kt visible to all
        asm volatile("" ::: "memory");

        const unsigned char* kb = lbuf[cur];

        // ---- S^T = K Q : lane holds P-row of q-row lr across 4 key groups ----
        f32x4 sacc[4];
        #pragma unroll
        for (int jt = 0; jt < 4; ++jt) sacc[jt] = f32x4{0.f, 0.f, 0.f, 0.f};
        #pragma unroll
        for (int jt = 0; jt < 4; ++jt) {
            const int j = jt * 16 + lr;                 // key row
            #pragma unroll
            for (int c = 0; c < 6; ++c) {
                f16x8 kf = *(const f16x8*)(kb + KFOFF +
                            ((j * 384 + c * 64 + lg * 16) ^ ((lr & 7) << 4)));
                sacc[jt] = __builtin_amdgcn_mfma_f32_16x16x32_f16(kf, qf[c], sacc[jt], 0, 0, 0);
            }
        }

        // ---- softmax (exp2 domain, defer-max) for own 16 rows ----
        float mloc;
        {
            float t0 = fmaxf(fmaxf(sacc[0][0], sacc[0][1]), fmaxf(sacc[0][2], sacc[0][3]));
            #pragma unroll
            for (int jt = 1; jt < 4; ++jt) {
                float t1 = fmaxf(fmaxf(sacc[jt][0], sacc[jt][1]), fmaxf(sacc[jt][2], sacc[jt][3]));
                t0 = fmaxf(t0, t1);
            }
            t0 = fmaxf(t0, __shfl_xor(t0, 16));
            t0 = fmaxf(t0, __shfl_xor(t0, 32));
            mloc = t0;
        }
        const bool need = (mloc > mrun + DEFER_THR);
        const float mnew = need ? mloc : mrun;
        const float alpha = exp2f(mrun - mnew);         // ==1.0f when !need; 0 on first tile
        mrun = mnew;
        if (lg == 0) a_lds[w * 16 + lr] = alpha;        // publish rescale factor for this row

        float ps = 0.f;
        f16x4 pk[4];
        #pragma unroll
        for (int jt = 0; jt < 4; ++jt)
            #pragma unroll
            for (int r = 0; r < 4; ++r) {
                const float p = exp2f(sacc[jt][r] - mrun);
                ps += p;
                pk[jt][r] = (_Float16)p;
            }
        ps += __shfl_xor(ps, 16);
        ps += __shfl_xor(ps, 32);
        lrun = lrun * alpha + ps;
        #pragma unroll
        for (int jt = 0; jt < 4; ++jt)
            *(f16x4*)(&P_lds[(w * 16 + lr) * PSTRIDE + jt * 16 + lg * 4]) = pk[jt];

        asm volatile("s_waitcnt lgkmcnt(0)" ::: "memory");
        __builtin_amdgcn_s_barrier();                   // B2: all P + alpha visible
        asm volatile("" ::: "memory");

        // ---- rescale acc by (possibly partner-computed) per-row alphas ----
        f32x4 al[2];
        al[0] = *(const f32x4*)&a_lds[pr + lg * 4];
        al[1] = *(const f32x4*)&a_lds[pr + 16 + lg * 4];
        const bool rs = (al[0][0] < 1.f) || (al[0][1] < 1.f) || (al[0][2] < 1.f) || (al[0][3] < 1.f) ||
                        (al[1][0] < 1.f) || (al[1][1] < 1.f) || (al[1][2] < 1.f) || (al[1][3] < 1.f);
        if (__ballot(rs)) {
            #pragma unroll
            for (int rg = 0; rg < 2; ++rg)
                #pragma unroll
                for (int dt = 0; dt < 9; ++dt)
                    #pragma unroll
                    for (int r = 0; r < 4; ++r) acc[rg][dt][r] *= al[rg][r];
        }

        // ---- O += P V : pair rows (2 rg), dim-half e (9 dt), vf shared across rg ----
        #pragma unroll
        for (int kc = 0; kc < 2; ++kc) {
            f16x8 pf0 = *(const f16x8*)(&P_lds[(pr + lr) * PSTRIDE + kc * 32 + lg * 8]);
            f16x8 pf1 = *(const f16x8*)(&P_lds[(pr + 16 + lr) * PSTRIDE + kc * 32 + lg * 8]);
            #pragma unroll
            for (int dt = 0; dt < 9; ++dt) {
                const int d = e * 144 + dt * 16 + lr;
                f16x8 vf = *(const f16x8*)(kb + VTOFF +
                            ((d * 128 + kc * 64 + lg * 16) ^ ((lr & 7) << 4)));
                acc[0][dt] = __builtin_amdgcn_mfma_f32_16x16x32_f16(pf0, vf, acc[0][dt], 0, 0, 0);
                acc[1][dt] = __builtin_amdgcn_mfma_f32_16x16x32_f16(pf1, vf, acc[1][dt], 0, 0, 0);
            }
        }

        asm volatile("" ::: "memory");
        __builtin_amdgcn_s_barrier();                   // B3: lbuf[cur] fully consumed
        cur ^= 1;
    }

    // ---- epilogue: share l across pair, out = acc / l ----
    if (lg == 0) a_lds[w * 16 + lr] = lrun;
    asm volatile("s_waitcnt lgkmcnt(0)" ::: "memory");
    __builtin_amdgcn_s_barrier();
    f32x4 lv[2];
    lv[0] = *(const f32x4*)&a_lds[pr + lg * 4];
    lv[1] = *(const f32x4*)&a_lds[pr + 16 + lg * 4];
    #pragma unroll
    for (int rg = 0; rg < 2; ++rg) {
        #pragma unroll
        for (int r = 0; r < 4; ++r) {
            const float inv = 1.0f / lv[rg][r];
            const int row = q0 + pr + rg * 16 + lg * 4 + r;
            float* omv = out + (rowbase + row) * 256;
            float* os  = out + 8388608ull + (rowbase + row) * 32;
            #pragma unroll
            for (int dt = 0; dt < 9; ++dt) {
                const int d = e * 144 + dt * 16 + lr;
                const float val = acc[rg][dt][r] * inv;
                if (d < 256) omv[d] = val;              // wave-uniform per dt
                else         os[d - 256] = val;
            }
        }
    }
}

// ---------------- fallback (R2 kernel): used only if ws is too small ----------------
#define FKSTRIDE 200
#define FVSTRIDE 72
__global__ __launch_bounds__(256, 2)
void geoattn_fallback(const float* __restrict__ q_mv, const float* __restrict__ k_mv,
                      const float* __restrict__ v_mv, const float* __restrict__ q_s,
                      const float* __restrict__ k_s, const float* __restrict__ v_s,
                      const float* __restrict__ logw, float* __restrict__ out)
{
    constexpr int IPIDX[8] = {0, 2, 3, 4, 8, 9, 10, 14};
    __shared__ __align__(16) _Float16 lds_k[64 * FKSTRIDE];
    __shared__ __align__(16) _Float16 lds_vt[288 * FVSTRIDE];
    __shared__ __align__(16) _Float16 lds_p[4 * 16 * FVSTRIDE];

    const int bid  = blockIdx.x;
    const int head = (bid & 7) | ((bid >> 8) << 3);
    const int qt   = (bid >> 3) & 31;
    const int h    = head & 7;
    const int tid  = threadIdx.x;
    const int w    = tid >> 6;
    const int lane = tid & 63;
    const int lr   = lane & 15;
    const int lg   = lane >> 4;
    const size_t rowbase = (size_t)head * NSEQ;
    const int q0 = qt * 64;
    const float scale = 0.07216878364870323f;

    f16x8 qf[6];
    {
        const int qrow = q0 + w * 16 + lr;
        const float* qmv = q_mv + (rowbase + qrow) * 256;
        const float* qs  = q_s  + (rowbase + qrow) * 32;
        #pragma unroll
        for (int c = 0; c < 4; ++c) {
            const int cmv = 4 * c + lg;
            const float wgt = __expf(logw[h * 16 + cmv]) * scale;
            const float* p = qmv + cmv * 16;
            #pragma unroll
            for (int i = 0; i < 8; ++i) qf[c][i] = (_Float16)(p[IPIDX[i]] * wgt);
        }
        const f32x4* p4 = (const f32x4*)(qs + lg * 8);
        f32x4 a = p4[0], b = p4[1];
        #pragma unroll
        for (int i = 0; i < 8; ++i) {
            float x = (i < 4) ? a[i & 3] : b[i & 3];
            qf[4][i] = (_Float16)(scale * x / (x * x + 1e-3f));
            qf[5][i] = (_Float16)(scale * x);
        }
    }
    f32x4 acc[18];
    #pragma unroll
    for (int dt = 0; dt < 18; ++dt) acc[dt] = f32x4{0.f, 0.f, 0.f, 0.f};
    float mrun[4] = {-1e30f, -1e30f, -1e30f, -1e30f};
    float lrun[4] = {0.f, 0.f, 0.f, 0.f};

    for (int kt = 0; kt < 32; ++kt) {
        const int j0 = kt * 64;
        __syncthreads();
        #pragma unroll
        for (int rep = 0; rep < 6; ++rep) {
            const int t = rep * 256 + tid;
            const int j = t & 63, oct = t >> 6;
            const size_t krow = rowbase + j0 + j;
            float v[8];
            if (oct < 16) {
                const float* p = k_mv + (krow * 16 + oct) * 16;
                #pragma unroll
                for (int i = 0; i < 8; ++i) v[i] = p[IPIDX[i]];
            } else if (oct < 20) {
                const f32x4* p4 = (const f32x4*)(k_s + krow * 32 + (oct - 16) * 8);
                f32x4 a = p4[0], b = p4[1];
                #pragma unroll
                for (int i = 0; i < 8; ++i) {
                    float x = (i < 4) ? a[i & 3] : b[i & 3];
                    v[i] = x / (x * x + 1e-3f);
                }
            } else {
                const f32x4* p4 = (const f32x4*)(k_s + krow * 32 + (oct - 20) * 8);
                f32x4 a = p4[0], b = p4[1];
                #pragma unroll
                for (int i = 0; i < 8; ++i) v[i] = (i < 4) ? a[i & 3] : b[i & 3];
            }
            f16x8 o;
            #pragma unroll
            for (int i = 0; i < 8; ++i) o[i] = (_Float16)v[i];
            *(f16x8*)(&lds_k[j * FKSTRIDE + oct * 8]) = o;
        }
        #pragma unroll
        for (int rep = 0; rep < 9; ++rep) {
            const int t = rep * 256 + tid;
            const int j = t & 63, oct = t >> 6;
            const size_t vrow = rowbase + j0 + j;
            const float* src = (oct < 32) ? (v_mv + vrow * 256 + oct * 8)
                                          : (v_s  + vrow * 32 + (oct - 32) * 8);
            const f32x4* p4 = (const f32x4*)src;
            f32x4 a = p4[0], b = p4[1];
            const int d0 = oct * 8;
            #pragma unroll
            for (int i = 0; i < 8; ++i)
                lds_vt[(d0 + i) * FVSTRIDE + j] = (_Float16)((i < 4) ? a[i & 3] : b[i & 3]);
        }
        __syncthreads();
        f32x4 sacc[4];
        #pragma unroll
        for (int nt = 0; nt < 4; ++nt) {
            sacc[nt] = f32x4{0.f, 0.f, 0.f, 0.f};
            #pragma unroll
            for (int c = 0; c < 6; ++c) {
                f16x8 kf = *(const f16x8*)(&lds_k[(lr + 16 * nt) * FKSTRIDE + 32 * c + lg * 8]);
                sacc[nt] = __builtin_amdgcn_mfma_f32_16x16x32_f16(qf[c], kf, sacc[nt], 0, 0, 0);
            }
        }
        float tmax[4], alpha[4];
        #pragma unroll
        for (int r = 0; r < 4; ++r) {
            float t0 = fmaxf(fmaxf(sacc[0][r], sacc[1][r]), fmaxf(sacc[2][r], sacc[3][r]));
            #pragma unroll
            for (int mm = 1; mm < 16; mm <<= 1) t0 = fmaxf(t0, __shfl_xor(t0, mm));
            tmax[r] = t0;
        }
        bool need = false;
        #pragma unroll
        for (int r = 0; r < 4; ++r) {
            float mnew = fmaxf(mrun[r], tmax[r]);
            need = need || (tmax[r] > mrun[r]);
            alpha[r] = __expf(mrun[r] - mnew);
            mrun[r] = mnew;
        }
        float pvv[4][4];
        float psum[4] = {0.f, 0.f, 0.f, 0.f};
        #pragma unroll
        for (int nt = 0; nt < 4; ++nt)
            #pragma unroll
            for (int r = 0; r < 4; ++r) {
                float p = __expf(sacc[nt][r] - mrun[r]);
                pvv[nt][r] = p;
                psum[r] += p;
            }
        #pragma unroll
        for (int r = 0; r < 4; ++r) {
            float s = psum[r];
            #pragma unroll
            for (int mm = 1; mm < 16; mm <<= 1) s += __shfl_xor(s, mm);
            lrun[r] = lrun[r] * alpha[r] + s;
        }
        if (__ballot(need)) {
            #pragma unroll
            for (int dt = 0; dt < 18; ++dt)
                #pragma unroll
                for (int r = 0; r < 4; ++r) acc[dt][r] *= alpha[r];
        }
        _Float16* pbf = &lds_p[w * 16 * FVSTRIDE];
        #pragma unroll
        for (int nt = 0; nt < 4; ++nt)
            #pragma unroll
            for (int r = 0; r < 4; ++r)
                pbf[(lg * 4 + r) * FVSTRIDE + lr + 16 * nt] = (_Float16)pvv[nt][r];
        #pragma unroll
        for (int ch = 0; ch < 2; ++ch) {
            f16x8 pf = *(const f16x8*)(&pbf[lr * FVSTRIDE + 32 * ch + lg * 8]);
            #pragma unroll
            for (int dt = 0; dt < 18; ++dt) {
                f16x8 vf = *(const f16x8*)(&lds_vt[(lr + 16 * dt) * FVSTRIDE + 32 * ch + lg * 8]);
                acc[dt] = __builtin_amdgcn_mfma_f32_16x16x32_f16(pf, vf, acc[dt], 0, 0, 0);
            }
        }
    }
    const int orow = q0 + w * 16 + lg * 4;
    #pragma unroll
    for (int r = 0; r < 4; ++r) {
        const float inv = 1.0f / lrun[r];
        float* omv = out + (rowbase + orow + r) * 256;
        float* os  = out + 8388608ull + (rowbase + orow + r) * 32;
        #pragma unroll
        for (int dt = 0; dt < 18; ++dt) {
            const int d = lr + 16 * dt;
            const float val = acc[dt][r] * inv;
            if (d < 256) omv[d] = val;
            else         os[d - 256] = val;
        }
    }
}

extern "C" void kernel_launch(void* const* d_in, const int* in_sizes, int n_in,
                              void* d_out, int out_size, void* d_ws, size_t ws_size,
                              hipStream_t stream) {
    (void)in_sizes; (void)n_in; (void)out_size;
    const float* q_mv = (const float*)d_in[0];
    const float* k_mv = (const float*)d_in[1];
    const float* v_mv = (const float*)d_in[2];
    const float* q_s  = (const float*)d_in[3];
    const float* k_s  = (const float*)d_in[4];
    const float* v_s  = (const float*)d_in[5];
    const float* logw = (const float*)d_in[6];
    float* out = (float*)d_out;

    if (ws_size >= WS_NEED) {
        unsigned char* ws = (unsigned char*)d_ws;
        prep_kf<<<dim3(512), dim3(256), 0, stream>>>(k_mv, k_s, ws);
        prep_vt<<<dim3(512), dim3(256), 0, stream>>>(v_mv, v_s, ws);
        geoattn_main<<<dim3(256), dim3(512), 0, stream>>>(q_mv, q_s, logw, ws, out);
    } else {
        geoattn_fallback<<<dim3(512), dim3(256), 0, stream>>>(q_mv, k_mv, v_mv, q_s, k_s, v_s, logw, out);
    }
}